// Round 8
// baseline (701.714 us; speedup 1.0000x reference)
//
#include <hip/hip_runtime.h>
#include <hip/hip_bf16.h>
#include <math.h>

#define N_ATOMS 16384
#define N_EDGES 262144
#define DIM 128
#define NF 128
#define NG 50
#define NL 4
#define NMOLS 32
#define EW 8   // waves per block
#define EB 4   // rows per wave batch (fp32 node gemm)

typedef short bf16x8 __attribute__((ext_vector_type(8)));
typedef float f32x4 __attribute__((ext_vector_type(4)));

__device__ __forceinline__ float ssp_f(float x) {
    // softplus(x) - log(2) = max(x,0) + log(1 + exp(-|x|)) - log(2)
    float e = __expf(-fabsf(x));
    return fmaxf(x, 0.0f) + __logf(1.0f + e) - 0.6931471805599453f;
}

__device__ __forceinline__ short f2bf(float x) {
    __hip_bfloat16 b = __float2bfloat16(x);  // RNE
    return *reinterpret_cast<short*>(&b);
}

// h[n][d] = z[n]*emb_W[d] + emb_b[d]
__global__ void k_embed(const float* __restrict__ z, const float* __restrict__ Wv,
                        const float* __restrict__ bv, float* __restrict__ h) {
    int idx = blockIdx.x * blockDim.x + threadIdx.x;
    int n = idx >> 7, d = idx & 127;
    h[idx] = z[n] * Wv[d] + bv[d];
}

// dist[e], C[e]
__global__ void k_geom(const float* __restrict__ pos, const int* __restrict__ src,
                       const int* __restrict__ dst, float* __restrict__ dist,
                       float* __restrict__ Cenv) {
    int e = blockIdx.x * blockDim.x + threadIdx.x;
    if (e >= N_EDGES) return;
    int s = src[e], t = dst[e];
    float dx = pos[3*s]   - pos[3*t];
    float dy = pos[3*s+1] - pos[3*t+1];
    float dz = pos[3*s+2] - pos[3*t+2];
    float d = sqrtf(dx*dx + dy*dy + dz*dz + 1e-12f);
    dist[e] = d;
    Cenv[e] = 0.5f * (cosf(d * (float)(M_PI / 5.0)) + 1.0f);
}

// ---- CSR build: sort edges by dst via counting sort ----
__global__ void k_deg(const int* __restrict__ dst, int* __restrict__ deg) {
    int e = blockIdx.x * blockDim.x + threadIdx.x;
    if (e < N_EDGES) atomicAdd(&deg[dst[e]], 1);
}

__global__ __launch_bounds__(1024)
void k_scan(const int* __restrict__ deg, int* __restrict__ cur) {
    __shared__ int tot[1024];
    int t = threadIdx.x;
    int v[16];
    int s = 0;
    #pragma unroll
    for (int j = 0; j < 16; ++j) { int x = deg[t * 16 + j]; v[j] = s; s += x; }
    tot[t] = s;
    __syncthreads();
    for (int off = 1; off < 1024; off <<= 1) {
        int add = (t >= off) ? tot[t - off] : 0;
        __syncthreads();
        tot[t] += add;
        __syncthreads();
    }
    int base = (t == 0) ? 0 : tot[t - 1];
    #pragma unroll
    for (int j = 0; j < 16; ++j) cur[t * 16 + j] = base + v[j];
}

__global__ void k_fill(const int* __restrict__ dst, int* __restrict__ cur,
                       int* __restrict__ edge_of) {
    int e = blockIdx.x * blockDim.x + threadIdx.x;
    if (e < N_EDGES) {
        int p = atomicAdd(&cur[dst[e]], 1);
        edge_of[p] = e;
    }
}

__global__ void k_perm(const int* __restrict__ edge_of, const float* __restrict__ dist,
                       const float* __restrict__ Cenv, const int* __restrict__ src,
                       const int* __restrict__ dst, float* __restrict__ distS,
                       float* __restrict__ CenvS, int* __restrict__ srcS,
                       int* __restrict__ dstS) {
    int p = blockIdx.x * blockDim.x + threadIdx.x;
    if (p >= N_EDGES) return;
    int e = edge_of[p];
    distS[p] = dist[e];
    CenvS[p] = Cenv[e];
    srcS[p]  = src[e];
    dstS[p]  = dst[e];
}

// Precompute rbf in MFMA A-fragment layout, SLOT order (layer-invariant, used 4x).
__global__ __launch_bounds__(512)
void k_rbf(const float* __restrict__ distS, short* __restrict__ rbfF) {
    int lane = threadIdx.x & 63;
    int w    = threadIdx.x >> 6;
    int t    = blockIdx.x * 8 + w;            // tile = 16 slots
    int q = lane >> 4, m = lane & 15;
    float d = distS[t * 16 + m];
    #pragma unroll
    for (int kc = 0; kc < 2; ++kc) {
        bf16x8 v;
        #pragma unroll
        for (int j = 0; j < 8; ++j) {
            float mu = (float)(kc * 32 + q * 8 + j) * (5.0f / 49.0f);
            float tt = d - mu;
            v[j] = f2bf(__expf(-4.0f * tt * tt));   // k>=50 rows hit zero W1R
        }
        *(bf16x8*)&rbfF[(size_t)((t * 2 + kc) * 64 + lane) * 8] = v;
    }
}

// MFMA edge pipeline over dst-sorted slots. Block = 8 waves; round = 64 slots.
// Single H1 buffer (barrier B orders matvec2 reads before next round's writes);
// xj gather issued right after barrier A so it flies during matvec2.
__global__ __launch_bounds__(512, 6)
void k_edge_csr(const short* __restrict__ rbfF, const float* __restrict__ CenvS,
                const int* __restrict__ srcS, const int* __restrict__ dstS,
                const float* __restrict__ W1, const float* __restrict__ b1,
                const float* __restrict__ W2, const float* __restrict__ b2,
                const float* __restrict__ xj, float* __restrict__ agg)
{
    __shared__ short H1s[64 * 128];      // 16 KB single buffer
    __shared__ float msgt[64][132];      // 33 KB message tile (+pad: bank-safe)
    __shared__ int dsts[64];
    __shared__ unsigned long long maskS;
    const int tid  = threadIdx.x;
    const int lane = tid & 63;
    const int w    = tid >> 6;     // wave id = filter block
    const int q    = lane >> 4;
    const int m    = lane & 15;

    bf16x8 W1R[2], W2R[4];
    #pragma unroll
    for (int kc = 0; kc < 2; ++kc) {
        bf16x8 f;
        #pragma unroll
        for (int j = 0; j < 8; ++j) {
            int k = kc * 32 + q * 8 + j;
            float v = (k < NG) ? W1[k * NF + w * 16 + m] : 0.0f;  // pad G 50->64
            f[j] = f2bf(v);
        }
        W1R[kc] = f;
    }
    #pragma unroll
    for (int kc = 0; kc < 4; ++kc) {
        bf16x8 f;
        #pragma unroll
        for (int j = 0; j < 8; ++j) {
            int k = kc * 32 + q * 8 + j;
            f[j] = f2bf(W2[k * NF + w * 16 + m]);
        }
        W2R[kc] = f;
    }
    const float b1v = b1[w * 16 + m];
    const float b2v = b2[w * 16 + m];

    const int nrounds = N_EDGES / 64;
    for (int r = blockIdx.x; r < nrounds; r += gridDim.x) {
        const int p0 = r * 64;
        short* H = H1s;

        // ---- matvec1: A from precomputed rbfF + ssp + swizzled H1 store ----
        #pragma unroll
        for (int a = 0; a < 4; ++a) {
            int tile = r * 4 + a;
            f32x4 acc = {b1v, b1v, b1v, b1v};
            #pragma unroll
            for (int kc = 0; kc < 2; ++kc) {
                bf16x8 A = *(const bf16x8*)&rbfF[(size_t)((tile * 2 + kc) * 64 + lane) * 8];
                acc = __builtin_amdgcn_mfma_f32_16x16x32_bf16(A, W1R[kc], acc, 0, 0, 0);
            }
            #pragma unroll
            for (int i = 0; i < 4; ++i) {
                int e = a * 16 + q * 4 + i;
                int f = w * 16 + m;
                int byte = (e * 256 + f * 2) ^ ((e & 7) << 4);
                *(short*)((char*)H + byte) = f2bf(ssp_f(acc[i]));
            }
        }
        __syncthreads();   // A: H1 write -> read

        // ---- issue xj gathers now; they fly during matvec2 (T14 issue-early) ----
        float xv[4][4];
        #pragma unroll
        for (int a = 0; a < 4; ++a) {
            int4 s4 = *(const int4*)&srcS[p0 + a * 16 + q * 4];
            #pragma unroll
            for (int i = 0; i < 4; ++i)
                xv[a][i] = xj[(size_t)((const int*)&s4)[i] * NF + w * 16 + m];
        }

        // ---- matvec2: Wf = H1 @ W2 + b2 ----
        f32x4 acc2[4];
        #pragma unroll
        for (int a = 0; a < 4; ++a) {
            f32x4 acc = {b2v, b2v, b2v, b2v};
            #pragma unroll
            for (int kc = 0; kc < 4; ++kc) {
                int e = a * 16 + m;
                int byte = (e * 256 + (kc * 32 + q * 8) * 2) ^ ((e & 7) << 4);
                bf16x8 A = *(const bf16x8*)((const char*)H + byte);  // ds_read_b128
                acc = __builtin_amdgcn_mfma_f32_16x16x32_bf16(A, W2R[kc], acc, 0, 0, 0);
            }
            acc2[a] = acc;
        }

        // ---- messages -> LDS tile (f32): v = Wf * C * xv ----
        #pragma unroll
        for (int a = 0; a < 4; ++a) {
            float4 cc4 = *(const float4*)&CenvS[p0 + a * 16 + q * 4];
            #pragma unroll
            for (int i = 0; i < 4; ++i) {
                float v = acc2[a][i] * ((const float*)&cc4)[i];
                msgt[a * 16 + q * 4 + i][w * 16 + m] = v * xv[a][i];
            }
        }
        if (w == 0) {
            int d = dstS[p0 + lane];
            int prev = __shfl_up(d, 1);
            bool head = (lane == 0) || (d != prev);
            unsigned long long mk = __ballot(head);
            dsts[lane] = d;
            if (lane == 0) maskS = mk;
        }
        __syncthreads();   // B: msgt/dsts write -> reduce

        // ---- run-segmented reduce: 128 threads (one per filter) x 4 run-groups ----
        {
            int f = tid & 127;
            int g = tid >> 7;
            unsigned long long mm = maskS;
            int k = 0;
            while (mm) {
                int start = __ffsll(mm) - 1;
                mm &= mm - 1;
                int end = mm ? (__ffsll(mm) - 1) : 64;
                if ((k & 3) == g) {
                    float s = 0.0f;
                    for (int p = start; p < end; ++p) s += msgt[p][f];
                    float* addr = &agg[(size_t)dsts[start] * NF + f];
                    if (start == 0 || end == 64) atomicAdd(addr, s);  // run may span rounds
                    else *addr = s;                                    // run exclusive here
                }
                ++k;
            }
        }
    }
}

// MFMA node GEMM: out[N,128] = post(in[N,128] @ W[128,128] + bias) (+ resid)
template<int ACT, int RESID>
__global__ __launch_bounds__(512, 2)
void k_node_mfma(const float* __restrict__ in, const float* __restrict__ W,
                 const float* __restrict__ bias, const float* __restrict__ resid,
                 float* __restrict__ out)
{
    __shared__ short T[64 * 128];   // 16 KB swizzled bf16 tile
    const int tid  = threadIdx.x;
    const int lane = tid & 63;
    const int w    = tid >> 6;
    const int q    = lane >> 4;
    const int m    = lane & 15;

    bf16x8 WR[4];
    #pragma unroll
    for (int kc = 0; kc < 4; ++kc) {
        bf16x8 f;
        #pragma unroll
        for (int j = 0; j < 8; ++j)
            f[j] = f2bf(W[(kc * 32 + q * 8 + j) * DIM + w * 16 + m]);
        WR[kc] = f;
    }
    const float bv = bias ? bias[w * 16 + m] : 0.0f;

    const int r0 = blockIdx.x * 64;

    {
        int row = tid >> 3;
        int k0  = (tid & 7) * 16;
        const float* src = in + (size_t)(r0 + row) * DIM + k0;
        float4 v0 = *(const float4*)(src);
        float4 v1 = *(const float4*)(src + 4);
        float4 v2 = *(const float4*)(src + 8);
        float4 v3 = *(const float4*)(src + 12);
        bf16x8 lo, hi;
        #pragma unroll
        for (int j = 0; j < 4; ++j) {
            lo[j]     = f2bf(((const float*)&v0)[j]);
            lo[j + 4] = f2bf(((const float*)&v1)[j]);
            hi[j]     = f2bf(((const float*)&v2)[j]);
            hi[j + 4] = f2bf(((const float*)&v3)[j]);
        }
        int b0 = (row * 256 + k0 * 2)       ^ ((row & 7) << 4);
        int b1 = (row * 256 + (k0 + 8) * 2) ^ ((row & 7) << 4);
        *(bf16x8*)((char*)T + b0) = lo;
        *(bf16x8*)((char*)T + b1) = hi;
    }
    __syncthreads();

    #pragma unroll
    for (int a = 0; a < 4; ++a) {
        f32x4 acc = {bv, bv, bv, bv};
        int row = a * 16 + m;
        #pragma unroll
        for (int kc = 0; kc < 4; ++kc) {
            int byte = (row * 256 + (kc * 32 + q * 8) * 2) ^ ((row & 7) << 4);
            bf16x8 A = *(const bf16x8*)((const char*)T + byte);
            acc = __builtin_amdgcn_mfma_f32_16x16x32_bf16(A, WR[kc], acc, 0, 0, 0);
        }
        #pragma unroll
        for (int i = 0; i < 4; ++i) {
            float v = acc[i];
            if (ACT) v = ssp_f(v);
            size_t oi = (size_t)(r0 + a * 16 + q * 4 + i) * DIM + w * 16 + m;
            if (RESID) v += resid[oi];
            out[oi] = v;
        }
    }
}

// fp32 node GEMM kept for lin1 (COLS=64)
template<int COLS, int ACT, int RESID>
__global__ __launch_bounds__(512)
void k_node_gemm(const float* __restrict__ in, const float* __restrict__ W,
                 const float* __restrict__ bias, const float* __restrict__ resid,
                 float* __restrict__ out)
{
    __shared__ float Ws[DIM][COLS];
    __shared__ float rs[EW][EB][DIM];
    int tid = threadIdx.x;
    for (int i = tid; i < DIM * COLS; i += 512) (&Ws[0][0])[i] = W[i];
    __syncthreads();

    int lane = tid & 63;
    int w = tid >> 6;
    int gw = blockIdx.x * EW + w;
    int nw = gridDim.x * EW;
    int ngroups = N_ATOMS / EB;
    constexpr int CPL = COLS / 64;

    float bb[CPL];
    #pragma unroll
    for (int c = 0; c < CPL; ++c) bb[c] = bias ? bias[lane + 64 * c] : 0.0f;

    for (int grp = gw; grp < ngroups; grp += nw) {
        int r0 = grp * EB;
        #pragma unroll
        for (int r = 0; r < EB; ++r) {
            rs[w][r][lane]      = in[(size_t)(r0 + r) * DIM + lane];
            rs[w][r][lane + 64] = in[(size_t)(r0 + r) * DIM + lane + 64];
        }
        float acc[EB][CPL];
        #pragma unroll
        for (int r = 0; r < EB; ++r)
            #pragma unroll
            for (int c = 0; c < CPL; ++c) acc[r][c] = bb[c];
        #pragma unroll 2
        for (int kb = 0; kb < DIM / 4; ++kb) {
            float4 rv[EB];
            #pragma unroll
            for (int r = 0; r < EB; ++r)
                rv[r] = *(const float4*)&rs[w][r][4 * kb];
            #pragma unroll
            for (int j = 0; j < 4; ++j) {
                float wv[CPL];
                #pragma unroll
                for (int c = 0; c < CPL; ++c) wv[c] = Ws[4 * kb + j][lane + 64 * c];
                #pragma unroll
                for (int r = 0; r < EB; ++r) {
                    float rj = ((const float*)&rv[r])[j];
                    #pragma unroll
                    for (int c = 0; c < CPL; ++c)
                        acc[r][c] = fmaf(rj, wv[c], acc[r][c]);
                }
            }
        }
        #pragma unroll
        for (int r = 0; r < EB; ++r) {
            #pragma unroll
            for (int c = 0; c < CPL; ++c) {
                float v = acc[r][c];
                if (ACT) v = ssp_f(v);
                size_t oi = (size_t)(r0 + r) * COLS + lane + 64 * c;
                if (RESID) v += resid[oi];
                out[oi] = v;
            }
        }
    }
}

// per-atom: dot(r1[n], lin2W) + lin2b -> per-block LDS mol reduce -> 32 atomics
__global__ __launch_bounds__(256)
void k_final(const float* __restrict__ r1, const float* __restrict__ l2W,
             const float* __restrict__ l2b, const int* __restrict__ batch,
             float* __restrict__ out)
{
    __shared__ float mols[NMOLS];
    int tid = threadIdx.x;
    if (tid < NMOLS) mols[tid] = 0.0f;
    __syncthreads();

    int n = blockIdx.x * 256 + tid;
    const float4* row = (const float4*)(r1 + (size_t)n * 64);
    const float4* wv  = (const float4*)l2W;
    float s = 0.0f;
    #pragma unroll
    for (int k = 0; k < 16; ++k) {
        float4 a = row[k], b = wv[k];
        s += a.x * b.x + a.y * b.y + a.z * b.z + a.w * b.w;
    }
    s += l2b[0];
    atomicAdd(&mols[batch[n]], s);   // LDS atomic (block-local)
    __syncthreads();
    if (tid < NMOLS) atomicAdd(&out[tid], mols[tid]);
}

extern "C" void kernel_launch(void* const* d_in, const int* in_sizes, int n_in,
                              void* d_out, int out_size, void* d_ws, size_t ws_size,
                              hipStream_t stream) {
    const float* z     = (const float*)d_in[0];
    const float* pos   = (const float*)d_in[1];
    const int*   batch = (const int*)d_in[2];
    const int*   esrc  = (const int*)d_in[3];
    const int*   edst  = (const int*)d_in[4];
    const float* embW  = (const float*)d_in[5];
    const float* embB  = (const float*)d_in[6];
    const float* mlpW1 = (const float*)d_in[7];
    const float* mlpB1 = (const float*)d_in[8];
    const float* mlpW2 = (const float*)d_in[9];
    const float* mlpB2 = (const float*)d_in[10];
    const float* cf1W  = (const float*)d_in[11];
    const float* cf2W  = (const float*)d_in[12];
    const float* cf2B  = (const float*)d_in[13];
    const float* intW  = (const float*)d_in[14];
    const float* intB  = (const float*)d_in[15];
    const float* l1W   = (const float*)d_in[16];
    const float* l1B   = (const float*)d_in[17];
    const float* l2W   = (const float*)d_in[18];
    const float* l2B   = (const float*)d_in[19];
    float* out = (float*)d_out;

    char* ws = (char*)d_ws;
    float* h     = (float*)(ws);                        // 8 MB
    float* dist  = (float*)(ws + (size_t)( 8 << 20));   // 1 MB
    float* Cv    = (float*)(ws + (size_t)( 9 << 20));   // 1 MB
    float* xj    = (float*)(ws + (size_t)(10 << 20));   // 8 MB (reused as tbuf)
    float* agg   = (float*)(ws + (size_t)(18 << 20));   // 8 MB (reused as r1)
    short* rbfF  = (short*)(ws + (size_t)(26 << 20));   // 32 MB bf16 A-fragments
    int*   deg   = (int*)  (ws + (size_t)(58 << 20));   // 64 KB
    int*   cur   = (int*)  (ws + (size_t)(59 << 20));   // 64 KB
    int*   edge_of = (int*)(ws + (size_t)(60 << 20));   // 1 MB
    float* distS = (float*)(ws + (size_t)(61 << 20));   // 1 MB
    float* CenvS = (float*)(ws + (size_t)(62 << 20));   // 1 MB
    int*   srcS  = (int*)  (ws + (size_t)(63 << 20));   // 1 MB
    int*   dstS  = (int*)  (ws + (size_t)(64 << 20));   // 1 MB
    float* tbuf = xj;
    float* r1   = agg;

    k_embed<<<dim3(N_ATOMS * DIM / 512), dim3(512), 0, stream>>>(z, embW, embB, h);
    k_geom<<<dim3(N_EDGES / 256), dim3(256), 0, stream>>>(pos, esrc, edst, dist, Cv);

    // CSR build (dst-sorted slot permutation)
    hipMemsetAsync(deg, 0, N_ATOMS * sizeof(int), stream);
    k_deg<<<dim3(N_EDGES / 512), dim3(512), 0, stream>>>(edst, deg);
    k_scan<<<dim3(1), dim3(1024), 0, stream>>>(deg, cur);
    k_fill<<<dim3(N_EDGES / 512), dim3(512), 0, stream>>>(edst, cur, edge_of);
    k_perm<<<dim3(N_EDGES / 512), dim3(512), 0, stream>>>(edge_of, dist, Cv, esrc, edst,
                                                          distS, CenvS, srcS, dstS);
    k_rbf<<<dim3(N_EDGES / 16 / 8), dim3(512), 0, stream>>>(distS, rbfF);

    for (int l = 0; l < NL; ++l) {
        k_node_mfma<0, 0><<<dim3(N_ATOMS / 64), dim3(512), 0, stream>>>(
            h, cf1W + (size_t)l * DIM * NF, nullptr, nullptr, xj);
        hipMemsetAsync(agg, 0, (size_t)N_ATOMS * NF * sizeof(float), stream);
        k_edge_csr<<<dim3(768), dim3(512), 0, stream>>>(
            rbfF, CenvS, srcS, dstS,
            mlpW1 + (size_t)l * NG * NF, mlpB1 + (size_t)l * NF,
            mlpW2 + (size_t)l * NF * NF, mlpB2 + (size_t)l * NF,
            xj, agg);
        k_node_mfma<1, 0><<<dim3(N_ATOMS / 64), dim3(512), 0, stream>>>(
            agg, cf2W + (size_t)l * NF * DIM, cf2B + (size_t)l * DIM, nullptr, tbuf);
        k_node_mfma<0, 1><<<dim3(N_ATOMS / 64), dim3(512), 0, stream>>>(
            tbuf, intW + (size_t)l * DIM * DIM, intB + (size_t)l * DIM, h, h);
    }

    k_node_gemm<64, 1, 0><<<dim3(256), dim3(512), 0, stream>>>(h, l1W, l1B, nullptr, r1);
    hipMemsetAsync(out, 0, NMOLS * sizeof(float), stream);
    k_final<<<dim3(N_ATOMS / 256), dim3(256), 0, stream>>>(r1, l2W, l2B, batch, out);
}

// Round 9
// 575.865 us; speedup vs baseline: 1.2185x; 1.2185x over previous
//
#include <hip/hip_runtime.h>
#include <hip/hip_bf16.h>
#include <math.h>

#define N_ATOMS 16384
#define N_EDGES 262144
#define DIM 128
#define NF 128
#define NG 50
#define NL 4
#define NMOLS 32
#define EW 8   // waves per block
#define EB 4   // rows per wave batch (fp32 node gemm)

typedef short bf16x8 __attribute__((ext_vector_type(8)));
typedef float f32x4 __attribute__((ext_vector_type(4)));

__device__ __forceinline__ float ssp_f(float x) {
    // softplus(x) - log(2) = max(x,0) + log(1 + exp(-|x|)) - log(2)
    float e = __expf(-fabsf(x));
    return fmaxf(x, 0.0f) + __logf(1.0f + e) - 0.6931471805599453f;
}

__device__ __forceinline__ short f2bf(float x) {
    __hip_bfloat16 b = __float2bfloat16(x);  // RNE
    return *reinterpret_cast<short*>(&b);
}

// h[n][d] = z[n]*emb_W[d] + emb_b[d]
__global__ void k_embed(const float* __restrict__ z, const float* __restrict__ Wv,
                        const float* __restrict__ bv, float* __restrict__ h) {
    int idx = blockIdx.x * blockDim.x + threadIdx.x;
    int n = idx >> 7, d = idx & 127;
    h[idx] = z[n] * Wv[d] + bv[d];
}

// dist[e], C[e]
__global__ void k_geom(const float* __restrict__ pos, const int* __restrict__ src,
                       const int* __restrict__ dst, float* __restrict__ dist,
                       float* __restrict__ Cenv) {
    int e = blockIdx.x * blockDim.x + threadIdx.x;
    if (e >= N_EDGES) return;
    int s = src[e], t = dst[e];
    float dx = pos[3*s]   - pos[3*t];
    float dy = pos[3*s+1] - pos[3*t+1];
    float dz = pos[3*s+2] - pos[3*t+2];
    float d = sqrtf(dx*dx + dy*dy + dz*dz + 1e-12f);
    dist[e] = d;
    Cenv[e] = 0.5f * (cosf(d * (float)(M_PI / 5.0)) + 1.0f);
}

// ---- CSR build: sort edges by dst via counting sort ----
__global__ void k_deg(const int* __restrict__ dst, int* __restrict__ deg) {
    int e = blockIdx.x * blockDim.x + threadIdx.x;
    if (e < N_EDGES) atomicAdd(&deg[dst[e]], 1);
}

__global__ __launch_bounds__(1024)
void k_scan(const int* __restrict__ deg, int* __restrict__ cur) {
    __shared__ int tot[1024];
    int t = threadIdx.x;
    int v[16];
    int s = 0;
    #pragma unroll
    for (int j = 0; j < 16; ++j) { int x = deg[t * 16 + j]; v[j] = s; s += x; }
    tot[t] = s;
    __syncthreads();
    for (int off = 1; off < 1024; off <<= 1) {
        int add = (t >= off) ? tot[t - off] : 0;
        __syncthreads();
        tot[t] += add;
        __syncthreads();
    }
    int base = (t == 0) ? 0 : tot[t - 1];
    #pragma unroll
    for (int j = 0; j < 16; ++j) cur[t * 16 + j] = base + v[j];
}

__global__ void k_fill(const int* __restrict__ dst, int* __restrict__ cur,
                       int* __restrict__ edge_of) {
    int e = blockIdx.x * blockDim.x + threadIdx.x;
    if (e < N_EDGES) {
        int p = atomicAdd(&cur[dst[e]], 1);
        edge_of[p] = e;
    }
}

__global__ void k_perm(const int* __restrict__ edge_of, const float* __restrict__ dist,
                       const float* __restrict__ Cenv, const int* __restrict__ src,
                       const int* __restrict__ dst, float* __restrict__ distS,
                       float* __restrict__ CenvS, int* __restrict__ srcS,
                       int* __restrict__ dstS) {
    int p = blockIdx.x * blockDim.x + threadIdx.x;
    if (p >= N_EDGES) return;
    int e = edge_of[p];
    distS[p] = dist[e];
    CenvS[p] = Cenv[e];
    srcS[p]  = src[e];
    dstS[p]  = dst[e];
}

// Precompute rbf in MFMA A-fragment layout, SLOT order (layer-invariant, used 4x).
__global__ __launch_bounds__(512)
void k_rbf(const float* __restrict__ distS, short* __restrict__ rbfF) {
    int lane = threadIdx.x & 63;
    int w    = threadIdx.x >> 6;
    int t    = blockIdx.x * 8 + w;            // tile = 16 slots
    int q = lane >> 4, m = lane & 15;
    float d = distS[t * 16 + m];
    #pragma unroll
    for (int kc = 0; kc < 2; ++kc) {
        bf16x8 v;
        #pragma unroll
        for (int j = 0; j < 8; ++j) {
            float mu = (float)(kc * 32 + q * 8 + j) * (5.0f / 49.0f);
            float tt = d - mu;
            v[j] = f2bf(__expf(-4.0f * tt * tt));   // k>=50 rows hit zero W1R
        }
        *(bf16x8*)&rbfF[(size_t)((t * 2 + kc) * 64 + lane) * 8] = v;
    }
}

// MFMA edge pipeline over dst-sorted slots. Block = 8 waves; round = 64 slots.
// Single H1 buffer; xj gather issued right after barrier A (flies during matvec2).
// launch_bounds(512,4): VGPR cap 128 — r8's (512,6) cap forced scratch spills
// (VGPR 40, +200MB HBM spill traffic); kernel naturally wants ~80 regs.
__global__ __launch_bounds__(512, 4)
void k_edge_csr(const short* __restrict__ rbfF, const float* __restrict__ CenvS,
                const int* __restrict__ srcS, const int* __restrict__ dstS,
                const float* __restrict__ W1, const float* __restrict__ b1,
                const float* __restrict__ W2, const float* __restrict__ b2,
                const float* __restrict__ xj, float* __restrict__ agg)
{
    __shared__ short H1s[64 * 128];      // 16 KB single buffer
    __shared__ float msgt[64][132];      // 33 KB message tile (+pad: bank-safe)
    __shared__ int dsts[64];
    __shared__ unsigned long long maskS;
    const int tid  = threadIdx.x;
    const int lane = tid & 63;
    const int w    = tid >> 6;     // wave id = filter block
    const int q    = lane >> 4;
    const int m    = lane & 15;

    bf16x8 W1R[2], W2R[4];
    #pragma unroll
    for (int kc = 0; kc < 2; ++kc) {
        bf16x8 f;
        #pragma unroll
        for (int j = 0; j < 8; ++j) {
            int k = kc * 32 + q * 8 + j;
            float v = (k < NG) ? W1[k * NF + w * 16 + m] : 0.0f;  // pad G 50->64
            f[j] = f2bf(v);
        }
        W1R[kc] = f;
    }
    #pragma unroll
    for (int kc = 0; kc < 4; ++kc) {
        bf16x8 f;
        #pragma unroll
        for (int j = 0; j < 8; ++j) {
            int k = kc * 32 + q * 8 + j;
            f[j] = f2bf(W2[k * NF + w * 16 + m]);
        }
        W2R[kc] = f;
    }
    const float b1v = b1[w * 16 + m];
    const float b2v = b2[w * 16 + m];

    const int nrounds = N_EDGES / 64;
    for (int r = blockIdx.x; r < nrounds; r += gridDim.x) {
        const int p0 = r * 64;
        short* H = H1s;

        // ---- matvec1: A from precomputed rbfF + ssp + swizzled H1 store ----
        #pragma unroll
        for (int a = 0; a < 4; ++a) {
            int tile = r * 4 + a;
            f32x4 acc = {b1v, b1v, b1v, b1v};
            #pragma unroll
            for (int kc = 0; kc < 2; ++kc) {
                bf16x8 A = *(const bf16x8*)&rbfF[(size_t)((tile * 2 + kc) * 64 + lane) * 8];
                acc = __builtin_amdgcn_mfma_f32_16x16x32_bf16(A, W1R[kc], acc, 0, 0, 0);
            }
            #pragma unroll
            for (int i = 0; i < 4; ++i) {
                int e = a * 16 + q * 4 + i;
                int f = w * 16 + m;
                int byte = (e * 256 + f * 2) ^ ((e & 7) << 4);
                *(short*)((char*)H + byte) = f2bf(ssp_f(acc[i]));
            }
        }
        __syncthreads();   // A: H1 write -> read

        // ---- issue xj gathers now; they fly during matvec2 (T14 issue-early) ----
        float xv[4][4];
        #pragma unroll
        for (int a = 0; a < 4; ++a) {
            int4 s4 = *(const int4*)&srcS[p0 + a * 16 + q * 4];
            #pragma unroll
            for (int i = 0; i < 4; ++i)
                xv[a][i] = xj[(size_t)((const int*)&s4)[i] * NF + w * 16 + m];
        }

        // ---- matvec2: Wf = H1 @ W2 + b2 ----
        f32x4 acc2[4];
        #pragma unroll
        for (int a = 0; a < 4; ++a) {
            f32x4 acc = {b2v, b2v, b2v, b2v};
            #pragma unroll
            for (int kc = 0; kc < 4; ++kc) {
                int e = a * 16 + m;
                int byte = (e * 256 + (kc * 32 + q * 8) * 2) ^ ((e & 7) << 4);
                bf16x8 A = *(const bf16x8*)((const char*)H + byte);  // ds_read_b128
                acc = __builtin_amdgcn_mfma_f32_16x16x32_bf16(A, W2R[kc], acc, 0, 0, 0);
            }
            acc2[a] = acc;
        }

        // ---- messages -> LDS tile (f32): v = Wf * C * xv ----
        #pragma unroll
        for (int a = 0; a < 4; ++a) {
            float4 cc4 = *(const float4*)&CenvS[p0 + a * 16 + q * 4];
            #pragma unroll
            for (int i = 0; i < 4; ++i) {
                float v = acc2[a][i] * ((const float*)&cc4)[i];
                msgt[a * 16 + q * 4 + i][w * 16 + m] = v * xv[a][i];
            }
        }
        if (w == 0) {
            int d = dstS[p0 + lane];
            int prev = __shfl_up(d, 1);
            bool head = (lane == 0) || (d != prev);
            unsigned long long mk = __ballot(head);
            dsts[lane] = d;
            if (lane == 0) maskS = mk;
        }
        __syncthreads();   // B: msgt/dsts write -> reduce

        // ---- run-segmented reduce: 128 threads (one per filter) x 4 run-groups ----
        {
            int f = tid & 127;
            int g = tid >> 7;
            unsigned long long mm = maskS;
            int k = 0;
            while (mm) {
                int start = __ffsll(mm) - 1;
                mm &= mm - 1;
                int end = mm ? (__ffsll(mm) - 1) : 64;
                if ((k & 3) == g) {
                    float s = 0.0f;
                    for (int p = start; p < end; ++p) s += msgt[p][f];
                    float* addr = &agg[(size_t)dsts[start] * NF + f];
                    if (start == 0 || end == 64) atomicAdd(addr, s);  // run may span rounds
                    else *addr = s;                                    // run exclusive here
                }
                ++k;
            }
        }
    }
}

// MFMA node GEMM: out[N,128] = post(in[N,128] @ W[128,128] + bias) (+ resid)
template<int ACT, int RESID>
__global__ __launch_bounds__(512, 2)
void k_node_mfma(const float* __restrict__ in, const float* __restrict__ W,
                 const float* __restrict__ bias, const float* __restrict__ resid,
                 float* __restrict__ out)
{
    __shared__ short T[64 * 128];   // 16 KB swizzled bf16 tile
    const int tid  = threadIdx.x;
    const int lane = tid & 63;
    const int w    = tid >> 6;
    const int q    = lane >> 4;
    const int m    = lane & 15;

    bf16x8 WR[4];
    #pragma unroll
    for (int kc = 0; kc < 4; ++kc) {
        bf16x8 f;
        #pragma unroll
        for (int j = 0; j < 8; ++j)
            f[j] = f2bf(W[(kc * 32 + q * 8 + j) * DIM + w * 16 + m]);
        WR[kc] = f;
    }
    const float bv = bias ? bias[w * 16 + m] : 0.0f;

    const int r0 = blockIdx.x * 64;

    {
        int row = tid >> 3;
        int k0  = (tid & 7) * 16;
        const float* src = in + (size_t)(r0 + row) * DIM + k0;
        float4 v0 = *(const float4*)(src);
        float4 v1 = *(const float4*)(src + 4);
        float4 v2 = *(const float4*)(src + 8);
        float4 v3 = *(const float4*)(src + 12);
        bf16x8 lo, hi;
        #pragma unroll
        for (int j = 0; j < 4; ++j) {
            lo[j]     = f2bf(((const float*)&v0)[j]);
            lo[j + 4] = f2bf(((const float*)&v1)[j]);
            hi[j]     = f2bf(((const float*)&v2)[j]);
            hi[j + 4] = f2bf(((const float*)&v3)[j]);
        }
        int b0 = (row * 256 + k0 * 2)       ^ ((row & 7) << 4);
        int b1 = (row * 256 + (k0 + 8) * 2) ^ ((row & 7) << 4);
        *(bf16x8*)((char*)T + b0) = lo;
        *(bf16x8*)((char*)T + b1) = hi;
    }
    __syncthreads();

    #pragma unroll
    for (int a = 0; a < 4; ++a) {
        f32x4 acc = {bv, bv, bv, bv};
        int row = a * 16 + m;
        #pragma unroll
        for (int kc = 0; kc < 4; ++kc) {
            int byte = (row * 256 + (kc * 32 + q * 8) * 2) ^ ((row & 7) << 4);
            bf16x8 A = *(const bf16x8*)((const char*)T + byte);
            acc = __builtin_amdgcn_mfma_f32_16x16x32_bf16(A, WR[kc], acc, 0, 0, 0);
        }
        #pragma unroll
        for (int i = 0; i < 4; ++i) {
            float v = acc[i];
            if (ACT) v = ssp_f(v);
            size_t oi = (size_t)(r0 + a * 16 + q * 4 + i) * DIM + w * 16 + m;
            if (RESID) v += resid[oi];
            out[oi] = v;
        }
    }
}

// fp32 node GEMM kept for lin1 (COLS=64)
template<int COLS, int ACT, int RESID>
__global__ __launch_bounds__(512)
void k_node_gemm(const float* __restrict__ in, const float* __restrict__ W,
                 const float* __restrict__ bias, const float* __restrict__ resid,
                 float* __restrict__ out)
{
    __shared__ float Ws[DIM][COLS];
    __shared__ float rs[EW][EB][DIM];
    int tid = threadIdx.x;
    for (int i = tid; i < DIM * COLS; i += 512) (&Ws[0][0])[i] = W[i];
    __syncthreads();

    int lane = tid & 63;
    int w = tid >> 6;
    int gw = blockIdx.x * EW + w;
    int nw = gridDim.x * EW;
    int ngroups = N_ATOMS / EB;
    constexpr int CPL = COLS / 64;

    float bb[CPL];
    #pragma unroll
    for (int c = 0; c < CPL; ++c) bb[c] = bias ? bias[lane + 64 * c] : 0.0f;

    for (int grp = gw; grp < ngroups; grp += nw) {
        int r0 = grp * EB;
        #pragma unroll
        for (int r = 0; r < EB; ++r) {
            rs[w][r][lane]      = in[(size_t)(r0 + r) * DIM + lane];
            rs[w][r][lane + 64] = in[(size_t)(r0 + r) * DIM + lane + 64];
        }
        float acc[EB][CPL];
        #pragma unroll
        for (int r = 0; r < EB; ++r)
            #pragma unroll
            for (int c = 0; c < CPL; ++c) acc[r][c] = bb[c];
        #pragma unroll 2
        for (int kb = 0; kb < DIM / 4; ++kb) {
            float4 rv[EB];
            #pragma unroll
            for (int r = 0; r < EB; ++r)
                rv[r] = *(const float4*)&rs[w][r][4 * kb];
            #pragma unroll
            for (int j = 0; j < 4; ++j) {
                float wv[CPL];
                #pragma unroll
                for (int c = 0; c < CPL; ++c) wv[c] = Ws[4 * kb + j][lane + 64 * c];
                #pragma unroll
                for (int r = 0; r < EB; ++r) {
                    float rj = ((const float*)&rv[r])[j];
                    #pragma unroll
                    for (int c = 0; c < CPL; ++c)
                        acc[r][c] = fmaf(rj, wv[c], acc[r][c]);
                }
            }
        }
        #pragma unroll
        for (int r = 0; r < EB; ++r) {
            #pragma unroll
            for (int c = 0; c < CPL; ++c) {
                float v = acc[r][c];
                if (ACT) v = ssp_f(v);
                size_t oi = (size_t)(r0 + r) * COLS + lane + 64 * c;
                if (RESID) v += resid[oi];
                out[oi] = v;
            }
        }
    }
}

// per-atom: dot(r1[n], lin2W) + lin2b -> per-block LDS mol reduce -> 32 atomics
__global__ __launch_bounds__(256)
void k_final(const float* __restrict__ r1, const float* __restrict__ l2W,
             const float* __restrict__ l2b, const int* __restrict__ batch,
             float* __restrict__ out)
{
    __shared__ float mols[NMOLS];
    int tid = threadIdx.x;
    if (tid < NMOLS) mols[tid] = 0.0f;
    __syncthreads();

    int n = blockIdx.x * 256 + tid;
    const float4* row = (const float4*)(r1 + (size_t)n * 64);
    const float4* wv  = (const float4*)l2W;
    float s = 0.0f;
    #pragma unroll
    for (int k = 0; k < 16; ++k) {
        float4 a = row[k], b = wv[k];
        s += a.x * b.x + a.y * b.y + a.z * b.z + a.w * b.w;
    }
    s += l2b[0];
    atomicAdd(&mols[batch[n]], s);   // LDS atomic (block-local)
    __syncthreads();
    if (tid < NMOLS) atomicAdd(&out[tid], mols[tid]);
}

extern "C" void kernel_launch(void* const* d_in, const int* in_sizes, int n_in,
                              void* d_out, int out_size, void* d_ws, size_t ws_size,
                              hipStream_t stream) {
    const float* z     = (const float*)d_in[0];
    const float* pos   = (const float*)d_in[1];
    const int*   batch = (const int*)d_in[2];
    const int*   esrc  = (const int*)d_in[3];
    const int*   edst  = (const int*)d_in[4];
    const float* embW  = (const float*)d_in[5];
    const float* embB  = (const float*)d_in[6];
    const float* mlpW1 = (const float*)d_in[7];
    const float* mlpB1 = (const float*)d_in[8];
    const float* mlpW2 = (const float*)d_in[9];
    const float* mlpB2 = (const float*)d_in[10];
    const float* cf1W  = (const float*)d_in[11];
    const float* cf2W  = (const float*)d_in[12];
    const float* cf2B  = (const float*)d_in[13];
    const float* intW  = (const float*)d_in[14];
    const float* intB  = (const float*)d_in[15];
    const float* l1W   = (const float*)d_in[16];
    const float* l1B   = (const float*)d_in[17];
    const float* l2W   = (const float*)d_in[18];
    const float* l2B   = (const float*)d_in[19];
    float* out = (float*)d_out;

    char* ws = (char*)d_ws;
    float* h     = (float*)(ws);                        // 8 MB
    float* dist  = (float*)(ws + (size_t)( 8 << 20));   // 1 MB
    float* Cv    = (float*)(ws + (size_t)( 9 << 20));   // 1 MB
    float* xj    = (float*)(ws + (size_t)(10 << 20));   // 8 MB (reused as tbuf)
    float* agg   = (float*)(ws + (size_t)(18 << 20));   // 8 MB (reused as r1)
    short* rbfF  = (short*)(ws + (size_t)(26 << 20));   // 32 MB bf16 A-fragments
    int*   deg   = (int*)  (ws + (size_t)(58 << 20));   // 64 KB
    int*   cur   = (int*)  (ws + (size_t)(59 << 20));   // 64 KB
    int*   edge_of = (int*)(ws + (size_t)(60 << 20));   // 1 MB
    float* distS = (float*)(ws + (size_t)(61 << 20));   // 1 MB
    float* CenvS = (float*)(ws + (size_t)(62 << 20));   // 1 MB
    int*   srcS  = (int*)  (ws + (size_t)(63 << 20));   // 1 MB
    int*   dstS  = (int*)  (ws + (size_t)(64 << 20));   // 1 MB
    float* tbuf = xj;
    float* r1   = agg;

    k_embed<<<dim3(N_ATOMS * DIM / 512), dim3(512), 0, stream>>>(z, embW, embB, h);
    k_geom<<<dim3(N_EDGES / 256), dim3(256), 0, stream>>>(pos, esrc, edst, dist, Cv);

    // CSR build (dst-sorted slot permutation)
    hipMemsetAsync(deg, 0, N_ATOMS * sizeof(int), stream);
    k_deg<<<dim3(N_EDGES / 512), dim3(512), 0, stream>>>(edst, deg);
    k_scan<<<dim3(1), dim3(1024), 0, stream>>>(deg, cur);
    k_fill<<<dim3(N_EDGES / 512), dim3(512), 0, stream>>>(edst, cur, edge_of);
    k_perm<<<dim3(N_EDGES / 512), dim3(512), 0, stream>>>(edge_of, dist, Cv, esrc, edst,
                                                          distS, CenvS, srcS, dstS);
    k_rbf<<<dim3(N_EDGES / 16 / 8), dim3(512), 0, stream>>>(distS, rbfF);

    for (int l = 0; l < NL; ++l) {
        k_node_mfma<0, 0><<<dim3(N_ATOMS / 64), dim3(512), 0, stream>>>(
            h, cf1W + (size_t)l * DIM * NF, nullptr, nullptr, xj);
        hipMemsetAsync(agg, 0, (size_t)N_ATOMS * NF * sizeof(float), stream);
        k_edge_csr<<<dim3(768), dim3(512), 0, stream>>>(
            rbfF, CenvS, srcS, dstS,
            mlpW1 + (size_t)l * NG * NF, mlpB1 + (size_t)l * NF,
            mlpW2 + (size_t)l * NF * NF, mlpB2 + (size_t)l * NF,
            xj, agg);
        k_node_mfma<1, 0><<<dim3(N_ATOMS / 64), dim3(512), 0, stream>>>(
            agg, cf2W + (size_t)l * NF * DIM, cf2B + (size_t)l * DIM, nullptr, tbuf);
        k_node_mfma<0, 1><<<dim3(N_ATOMS / 64), dim3(512), 0, stream>>>(
            tbuf, intW + (size_t)l * DIM * DIM, intB + (size_t)l * DIM, h, h);
    }

    k_node_gemm<64, 1, 0><<<dim3(256), dim3(512), 0, stream>>>(h, l1W, l1B, nullptr, r1);
    hipMemsetAsync(out, 0, NMOLS * sizeof(float), stream);
    k_final<<<dim3(N_ATOMS / 256), dim3(256), 0, stream>>>(r1, l2W, l2B, batch, out);
}

// Round 10
// 526.617 us; speedup vs baseline: 1.3325x; 1.0935x over previous
//
#include <hip/hip_runtime.h>
#include <hip/hip_bf16.h>
#include <math.h>

#define N_ATOMS 16384
#define N_EDGES 262144
#define DIM 128
#define NF 128
#define NG 50
#define NL 4
#define NMOLS 32
#define EW 8   // waves per block
#define EB 4   // rows per wave batch (fp32 node gemm)

typedef short bf16x8 __attribute__((ext_vector_type(8)));
typedef float f32x4 __attribute__((ext_vector_type(4)));

__device__ __forceinline__ float ssp_f(float x) {
    // softplus(x) - log(2) = max(x,0) + log(1 + exp(-|x|)) - log(2)
    float e = __expf(-fabsf(x));
    return fmaxf(x, 0.0f) + __logf(1.0f + e) - 0.6931471805599453f;
}

__device__ __forceinline__ short f2bf(float x) {
    __hip_bfloat16 b = __float2bfloat16(x);  // RNE
    return *reinterpret_cast<short*>(&b);
}

__device__ __forceinline__ float bf2f(unsigned short u) {
    unsigned int v = ((unsigned int)u) << 16;
    return __builtin_bit_cast(float, v);
}

// h[n][d] = z[n]*emb_W[d] + emb_b[d]
__global__ void k_embed(const float* __restrict__ z, const float* __restrict__ Wv,
                        const float* __restrict__ bv, float* __restrict__ h) {
    int idx = blockIdx.x * blockDim.x + threadIdx.x;
    int n = idx >> 7, d = idx & 127;
    h[idx] = z[n] * Wv[d] + bv[d];
}

// dist[e], C[e]
__global__ void k_geom(const float* __restrict__ pos, const int* __restrict__ src,
                       const int* __restrict__ dst, float* __restrict__ dist,
                       float* __restrict__ Cenv) {
    int e = blockIdx.x * blockDim.x + threadIdx.x;
    if (e >= N_EDGES) return;
    int s = src[e], t = dst[e];
    float dx = pos[3*s]   - pos[3*t];
    float dy = pos[3*s+1] - pos[3*t+1];
    float dz = pos[3*s+2] - pos[3*t+2];
    float d = sqrtf(dx*dx + dy*dy + dz*dz + 1e-12f);
    dist[e] = d;
    Cenv[e] = 0.5f * (cosf(d * (float)(M_PI / 5.0)) + 1.0f);
}

// ---- CSR build: sort edges by dst via counting sort ----
__global__ void k_deg(const int* __restrict__ dst, int* __restrict__ deg) {
    int e = blockIdx.x * blockDim.x + threadIdx.x;
    if (e < N_EDGES) atomicAdd(&deg[dst[e]], 1);
}

__global__ __launch_bounds__(1024)
void k_scan(const int* __restrict__ deg, int* __restrict__ cur) {
    __shared__ int tot[1024];
    int t = threadIdx.x;
    int v[16];
    int s = 0;
    #pragma unroll
    for (int j = 0; j < 16; ++j) { int x = deg[t * 16 + j]; v[j] = s; s += x; }
    tot[t] = s;
    __syncthreads();
    for (int off = 1; off < 1024; off <<= 1) {
        int add = (t >= off) ? tot[t - off] : 0;
        __syncthreads();
        tot[t] += add;
        __syncthreads();
    }
    int base = (t == 0) ? 0 : tot[t - 1];
    #pragma unroll
    for (int j = 0; j < 16; ++j) cur[t * 16 + j] = base + v[j];
}

__global__ void k_fill(const int* __restrict__ dst, int* __restrict__ cur,
                       int* __restrict__ edge_of) {
    int e = blockIdx.x * blockDim.x + threadIdx.x;
    if (e < N_EDGES) {
        int p = atomicAdd(&cur[dst[e]], 1);
        edge_of[p] = e;
    }
}

__global__ void k_perm(const int* __restrict__ edge_of, const float* __restrict__ dist,
                       const float* __restrict__ Cenv, const int* __restrict__ src,
                       const int* __restrict__ dst, float* __restrict__ distS,
                       float* __restrict__ CenvS, int* __restrict__ srcS,
                       int* __restrict__ dstS) {
    int p = blockIdx.x * blockDim.x + threadIdx.x;
    if (p >= N_EDGES) return;
    int e = edge_of[p];
    distS[p] = dist[e];
    CenvS[p] = Cenv[e];
    srcS[p]  = src[e];
    dstS[p]  = dst[e];
}

// Precompute rbf in MFMA A-fragment layout, SLOT order (layer-invariant, used 4x).
__global__ __launch_bounds__(512)
void k_rbf(const float* __restrict__ distS, short* __restrict__ rbfF) {
    int lane = threadIdx.x & 63;
    int w    = threadIdx.x >> 6;
    int t    = blockIdx.x * 8 + w;            // tile = 16 slots
    int q = lane >> 4, m = lane & 15;
    float d = distS[t * 16 + m];
    #pragma unroll
    for (int kc = 0; kc < 2; ++kc) {
        bf16x8 v;
        #pragma unroll
        for (int j = 0; j < 8; ++j) {
            float mu = (float)(kc * 32 + q * 8 + j) * (5.0f / 49.0f);
            float tt = d - mu;
            v[j] = f2bf(__expf(-4.0f * tt * tt));   // k>=50 rows hit zero W1R
        }
        *(bf16x8*)&rbfF[(size_t)((t * 2 + kc) * 64 + lane) * 8] = v;
    }
}

// MFMA edge pipeline over dst-sorted slots. Block = 8 waves; round = 64 slots.
// xj is bf16 (4 MB -> fits per-XCD L2; gather row 256B); msgt is bf16 LDS
// (block LDS ~34 KB -> 4 blocks/CU at VGPR<=64). Sums stay fp32.
__global__ __launch_bounds__(512, 4)
void k_edge_csr(const short* __restrict__ rbfF, const float* __restrict__ CenvS,
                const int* __restrict__ srcS, const int* __restrict__ dstS,
                const float* __restrict__ W1, const float* __restrict__ b1,
                const float* __restrict__ W2, const float* __restrict__ b2,
                const unsigned short* __restrict__ xjb, float* __restrict__ agg)
{
    __shared__ short H1s[64 * 128];              // 16 KB
    __shared__ unsigned short msgt[64][136];     // 17 KB bf16 message tile (+16B pad)
    __shared__ int dsts[64];
    __shared__ unsigned long long maskS;
    const int tid  = threadIdx.x;
    const int lane = tid & 63;
    const int w    = tid >> 6;     // wave id = filter block
    const int q    = lane >> 4;
    const int m    = lane & 15;

    bf16x8 W1R[2], W2R[4];
    #pragma unroll
    for (int kc = 0; kc < 2; ++kc) {
        bf16x8 f;
        #pragma unroll
        for (int j = 0; j < 8; ++j) {
            int k = kc * 32 + q * 8 + j;
            float v = (k < NG) ? W1[k * NF + w * 16 + m] : 0.0f;  // pad G 50->64
            f[j] = f2bf(v);
        }
        W1R[kc] = f;
    }
    #pragma unroll
    for (int kc = 0; kc < 4; ++kc) {
        bf16x8 f;
        #pragma unroll
        for (int j = 0; j < 8; ++j) {
            int k = kc * 32 + q * 8 + j;
            f[j] = f2bf(W2[k * NF + w * 16 + m]);
        }
        W2R[kc] = f;
    }
    const float b1v = b1[w * 16 + m];
    const float b2v = b2[w * 16 + m];

    const int nrounds = N_EDGES / 64;
    for (int r = blockIdx.x; r < nrounds; r += gridDim.x) {
        const int p0 = r * 64;
        short* H = H1s;

        // ---- matvec1: A from precomputed rbfF + ssp + swizzled H1 store ----
        #pragma unroll
        for (int a = 0; a < 4; ++a) {
            int tile = r * 4 + a;
            f32x4 acc = {b1v, b1v, b1v, b1v};
            #pragma unroll
            for (int kc = 0; kc < 2; ++kc) {
                bf16x8 A = *(const bf16x8*)&rbfF[(size_t)((tile * 2 + kc) * 64 + lane) * 8];
                acc = __builtin_amdgcn_mfma_f32_16x16x32_bf16(A, W1R[kc], acc, 0, 0, 0);
            }
            #pragma unroll
            for (int i = 0; i < 4; ++i) {
                int e = a * 16 + q * 4 + i;
                int f = w * 16 + m;
                int byte = (e * 256 + f * 2) ^ ((e & 7) << 4);
                *(short*)((char*)H + byte) = f2bf(ssp_f(acc[i]));
            }
        }
        __syncthreads();   // A: H1 write -> read

        // ---- issue xj gathers now; they fly during matvec2 (T14 issue-early) ----
        unsigned short xu[4][4];
        #pragma unroll
        for (int a = 0; a < 4; ++a) {
            int4 s4 = *(const int4*)&srcS[p0 + a * 16 + q * 4];
            #pragma unroll
            for (int i = 0; i < 4; ++i)
                xu[a][i] = xjb[(size_t)((const int*)&s4)[i] * NF + w * 16 + m];
        }

        // ---- matvec2: Wf = H1 @ W2 + b2 ----
        f32x4 acc2[4];
        #pragma unroll
        for (int a = 0; a < 4; ++a) {
            f32x4 acc = {b2v, b2v, b2v, b2v};
            #pragma unroll
            for (int kc = 0; kc < 4; ++kc) {
                int e = a * 16 + m;
                int byte = (e * 256 + (kc * 32 + q * 8) * 2) ^ ((e & 7) << 4);
                bf16x8 A = *(const bf16x8*)((const char*)H + byte);  // ds_read_b128
                acc = __builtin_amdgcn_mfma_f32_16x16x32_bf16(A, W2R[kc], acc, 0, 0, 0);
            }
            acc2[a] = acc;
        }

        // ---- messages -> LDS tile (bf16): v = Wf * C * xv ----
        #pragma unroll
        for (int a = 0; a < 4; ++a) {
            float4 cc4 = *(const float4*)&CenvS[p0 + a * 16 + q * 4];
            #pragma unroll
            for (int i = 0; i < 4; ++i) {
                float v = acc2[a][i] * ((const float*)&cc4)[i];
                msgt[a * 16 + q * 4 + i][w * 16 + m] =
                    (unsigned short)f2bf(v * bf2f(xu[a][i]));
            }
        }
        if (w == 0) {
            int d = dstS[p0 + lane];
            int prev = __shfl_up(d, 1);
            bool head = (lane == 0) || (d != prev);
            unsigned long long mk = __ballot(head);
            dsts[lane] = d;
            if (lane == 0) maskS = mk;
        }
        __syncthreads();   // B: msgt/dsts write -> reduce

        // ---- run-segmented reduce: 128 threads (one per filter) x 4 run-groups ----
        {
            int f = tid & 127;
            int g = tid >> 7;
            unsigned long long mm = maskS;
            int k = 0;
            while (mm) {
                int start = __ffsll(mm) - 1;
                mm &= mm - 1;
                int end = mm ? (__ffsll(mm) - 1) : 64;
                if ((k & 3) == g) {
                    float s = 0.0f;
                    for (int p = start; p < end; ++p) s += bf2f(msgt[p][f]);
                    float* addr = &agg[(size_t)dsts[start] * NF + f];
                    if (start == 0 || end == 64) atomicAdd(addr, s);  // run may span rounds
                    else *addr = s;                                    // run exclusive here
                }
                ++k;
            }
        }
    }
}

// MFMA node GEMM: out[N,128] = post(in[N,128] @ W[128,128] + bias) (+ resid)
// OUTBF: write bf16 (ushort) output instead of f32.
template<int ACT, int RESID, int OUTBF>
__global__ __launch_bounds__(512, 2)
void k_node_mfma(const float* __restrict__ in, const float* __restrict__ W,
                 const float* __restrict__ bias, const float* __restrict__ resid,
                 void* __restrict__ outv)
{
    __shared__ short T[64 * 128];   // 16 KB swizzled bf16 tile
    const int tid  = threadIdx.x;
    const int lane = tid & 63;
    const int w    = tid >> 6;
    const int q    = lane >> 4;
    const int m    = lane & 15;

    bf16x8 WR[4];
    #pragma unroll
    for (int kc = 0; kc < 4; ++kc) {
        bf16x8 f;
        #pragma unroll
        for (int j = 0; j < 8; ++j)
            f[j] = f2bf(W[(kc * 32 + q * 8 + j) * DIM + w * 16 + m]);
        WR[kc] = f;
    }
    const float bv = bias ? bias[w * 16 + m] : 0.0f;

    const int r0 = blockIdx.x * 64;

    {
        int row = tid >> 3;
        int k0  = (tid & 7) * 16;
        const float* src = in + (size_t)(r0 + row) * DIM + k0;
        float4 v0 = *(const float4*)(src);
        float4 v1 = *(const float4*)(src + 4);
        float4 v2 = *(const float4*)(src + 8);
        float4 v3 = *(const float4*)(src + 12);
        bf16x8 lo, hi;
        #pragma unroll
        for (int j = 0; j < 4; ++j) {
            lo[j]     = f2bf(((const float*)&v0)[j]);
            lo[j + 4] = f2bf(((const float*)&v1)[j]);
            hi[j]     = f2bf(((const float*)&v2)[j]);
            hi[j + 4] = f2bf(((const float*)&v3)[j]);
        }
        int b0 = (row * 256 + k0 * 2)       ^ ((row & 7) << 4);
        int b1 = (row * 256 + (k0 + 8) * 2) ^ ((row & 7) << 4);
        *(bf16x8*)((char*)T + b0) = lo;
        *(bf16x8*)((char*)T + b1) = hi;
    }
    __syncthreads();

    #pragma unroll
    for (int a = 0; a < 4; ++a) {
        f32x4 acc = {bv, bv, bv, bv};
        int row = a * 16 + m;
        #pragma unroll
        for (int kc = 0; kc < 4; ++kc) {
            int byte = (row * 256 + (kc * 32 + q * 8) * 2) ^ ((row & 7) << 4);
            bf16x8 A = *(const bf16x8*)((const char*)T + byte);
            acc = __builtin_amdgcn_mfma_f32_16x16x32_bf16(A, WR[kc], acc, 0, 0, 0);
        }
        #pragma unroll
        for (int i = 0; i < 4; ++i) {
            float v = acc[i];
            if (ACT) v = ssp_f(v);
            size_t oi = (size_t)(r0 + a * 16 + q * 4 + i) * DIM + w * 16 + m;
            if (RESID) v += ((const float*)outv == nullptr ? 0.0f : resid[oi]);
            if (OUTBF) ((unsigned short*)outv)[oi] = (unsigned short)f2bf(v);
            else       ((float*)outv)[oi] = v;
        }
    }
}

// fp32 node GEMM kept for lin1 (COLS=64)
template<int COLS, int ACT, int RESID>
__global__ __launch_bounds__(512)
void k_node_gemm(const float* __restrict__ in, const float* __restrict__ W,
                 const float* __restrict__ bias, const float* __restrict__ resid,
                 float* __restrict__ out)
{
    __shared__ float Ws[DIM][COLS];
    __shared__ float rs[EW][EB][DIM];
    int tid = threadIdx.x;
    for (int i = tid; i < DIM * COLS; i += 512) (&Ws[0][0])[i] = W[i];
    __syncthreads();

    int lane = tid & 63;
    int w = tid >> 6;
    int gw = blockIdx.x * EW + w;
    int nw = gridDim.x * EW;
    int ngroups = N_ATOMS / EB;
    constexpr int CPL = COLS / 64;

    float bb[CPL];
    #pragma unroll
    for (int c = 0; c < CPL; ++c) bb[c] = bias ? bias[lane + 64 * c] : 0.0f;

    for (int grp = gw; grp < ngroups; grp += nw) {
        int r0 = grp * EB;
        #pragma unroll
        for (int r = 0; r < EB; ++r) {
            rs[w][r][lane]      = in[(size_t)(r0 + r) * DIM + lane];
            rs[w][r][lane + 64] = in[(size_t)(r0 + r) * DIM + lane + 64];
        }
        float acc[EB][CPL];
        #pragma unroll
        for (int r = 0; r < EB; ++r)
            #pragma unroll
            for (int c = 0; c < CPL; ++c) acc[r][c] = bb[c];
        #pragma unroll 2
        for (int kb = 0; kb < DIM / 4; ++kb) {
            float4 rv[EB];
            #pragma unroll
            for (int r = 0; r < EB; ++r)
                rv[r] = *(const float4*)&rs[w][r][4 * kb];
            #pragma unroll
            for (int j = 0; j < 4; ++j) {
                float wv[CPL];
                #pragma unroll
                for (int c = 0; c < CPL; ++c) wv[c] = Ws[4 * kb + j][lane + 64 * c];
                #pragma unroll
                for (int r = 0; r < EB; ++r) {
                    float rj = ((const float*)&rv[r])[j];
                    #pragma unroll
                    for (int c = 0; c < CPL; ++c)
                        acc[r][c] = fmaf(rj, wv[c], acc[r][c]);
                }
            }
        }
        #pragma unroll
        for (int r = 0; r < EB; ++r) {
            #pragma unroll
            for (int c = 0; c < CPL; ++c) {
                float v = acc[r][c];
                if (ACT) v = ssp_f(v);
                size_t oi = (size_t)(r0 + r) * COLS + lane + 64 * c;
                if (RESID) v += resid[oi];
                out[oi] = v;
            }
        }
    }
}

// per-atom: dot(r1[n], lin2W) + lin2b -> per-block LDS mol reduce -> 32 atomics
__global__ __launch_bounds__(256)
void k_final(const float* __restrict__ r1, const float* __restrict__ l2W,
             const float* __restrict__ l2b, const int* __restrict__ batch,
             float* __restrict__ out)
{
    __shared__ float mols[NMOLS];
    int tid = threadIdx.x;
    if (tid < NMOLS) mols[tid] = 0.0f;
    __syncthreads();

    int n = blockIdx.x * 256 + tid;
    const float4* row = (const float4*)(r1 + (size_t)n * 64);
    const float4* wv  = (const float4*)l2W;
    float s = 0.0f;
    #pragma unroll
    for (int k = 0; k < 16; ++k) {
        float4 a = row[k], b = wv[k];
        s += a.x * b.x + a.y * b.y + a.z * b.z + a.w * b.w;
    }
    s += l2b[0];
    atomicAdd(&mols[batch[n]], s);   // LDS atomic (block-local)
    __syncthreads();
    if (tid < NMOLS) atomicAdd(&out[tid], mols[tid]);
}

extern "C" void kernel_launch(void* const* d_in, const int* in_sizes, int n_in,
                              void* d_out, int out_size, void* d_ws, size_t ws_size,
                              hipStream_t stream) {
    const float* z     = (const float*)d_in[0];
    const float* pos   = (const float*)d_in[1];
    const int*   batch = (const int*)d_in[2];
    const int*   esrc  = (const int*)d_in[3];
    const int*   edst  = (const int*)d_in[4];
    const float* embW  = (const float*)d_in[5];
    const float* embB  = (const float*)d_in[6];
    const float* mlpW1 = (const float*)d_in[7];
    const float* mlpB1 = (const float*)d_in[8];
    const float* mlpW2 = (const float*)d_in[9];
    const float* mlpB2 = (const float*)d_in[10];
    const float* cf1W  = (const float*)d_in[11];
    const float* cf2W  = (const float*)d_in[12];
    const float* cf2B  = (const float*)d_in[13];
    const float* intW  = (const float*)d_in[14];
    const float* intB  = (const float*)d_in[15];
    const float* l1W   = (const float*)d_in[16];
    const float* l1B   = (const float*)d_in[17];
    const float* l2W   = (const float*)d_in[18];
    const float* l2B   = (const float*)d_in[19];
    float* out = (float*)d_out;

    char* ws = (char*)d_ws;
    float* h     = (float*)(ws);                        // 8 MB
    float* dist  = (float*)(ws + (size_t)( 8 << 20));   // 1 MB
    float* Cv    = (float*)(ws + (size_t)( 9 << 20));   // 1 MB
    unsigned short* xj = (unsigned short*)(ws + (size_t)(10 << 20)); // 4 MB bf16
    float* tbuf  = (float*)(ws + (size_t)(10 << 20));   // 8 MB (aliases xj; liveness-disjoint)
    float* agg   = (float*)(ws + (size_t)(18 << 20));   // 8 MB (reused as r1)
    short* rbfF  = (short*)(ws + (size_t)(26 << 20));   // 32 MB bf16 A-fragments
    int*   deg   = (int*)  (ws + (size_t)(58 << 20));   // 64 KB
    int*   cur   = (int*)  (ws + (size_t)(59 << 20));   // 64 KB
    int*   edge_of = (int*)(ws + (size_t)(60 << 20));   // 1 MB
    float* distS = (float*)(ws + (size_t)(61 << 20));   // 1 MB
    float* CenvS = (float*)(ws + (size_t)(62 << 20));   // 1 MB
    int*   srcS  = (int*)  (ws + (size_t)(63 << 20));   // 1 MB
    int*   dstS  = (int*)  (ws + (size_t)(64 << 20));   // 1 MB
    float* r1    = agg;

    k_embed<<<dim3(N_ATOMS * DIM / 512), dim3(512), 0, stream>>>(z, embW, embB, h);
    k_geom<<<dim3(N_EDGES / 256), dim3(256), 0, stream>>>(pos, esrc, edst, dist, Cv);

    // CSR build (dst-sorted slot permutation)
    hipMemsetAsync(deg, 0, N_ATOMS * sizeof(int), stream);
    k_deg<<<dim3(N_EDGES / 512), dim3(512), 0, stream>>>(edst, deg);
    k_scan<<<dim3(1), dim3(1024), 0, stream>>>(deg, cur);
    k_fill<<<dim3(N_EDGES / 512), dim3(512), 0, stream>>>(edst, cur, edge_of);
    k_perm<<<dim3(N_EDGES / 512), dim3(512), 0, stream>>>(edge_of, dist, Cv, esrc, edst,
                                                          distS, CenvS, srcS, dstS);
    k_rbf<<<dim3(N_EDGES / 16 / 8), dim3(512), 0, stream>>>(distS, rbfF);

    for (int l = 0; l < NL; ++l) {
        // cf1: h @ cf1W -> xj (bf16 out). Note: tbuf (aliased) is dead here.
        k_node_mfma<0, 0, 1><<<dim3(N_ATOMS / 64), dim3(512), 0, stream>>>(
            h, cf1W + (size_t)l * DIM * NF, nullptr, nullptr, (void*)xj);
        hipMemsetAsync(agg, 0, (size_t)N_ATOMS * NF * sizeof(float), stream);
        k_edge_csr<<<dim3(1024), dim3(512), 0, stream>>>(
            rbfF, CenvS, srcS, dstS,
            mlpW1 + (size_t)l * NG * NF, mlpB1 + (size_t)l * NF,
            mlpW2 + (size_t)l * NF * NF, mlpB2 + (size_t)l * NF,
            xj, agg);
        // cf2: ssp(agg @ cf2W + b) -> tbuf (xj dead now; alias safe)
        k_node_mfma<1, 0, 0><<<dim3(N_ATOMS / 64), dim3(512), 0, stream>>>(
            agg, cf2W + (size_t)l * NF * DIM, cf2B + (size_t)l * DIM, nullptr, (void*)tbuf);
        // int_lin: tbuf @ intW + b + h -> h
        k_node_mfma<0, 1, 0><<<dim3(N_ATOMS / 64), dim3(512), 0, stream>>>(
            tbuf, intW + (size_t)l * DIM * DIM, intB + (size_t)l * DIM, h, (void*)h);
    }

    k_node_gemm<64, 1, 0><<<dim3(256), dim3(512), 0, stream>>>(h, l1W, l1B, nullptr, r1);
    hipMemsetAsync(out, 0, NMOLS * sizeof(float), stream);
    k_final<<<dim3(N_ATOMS / 256), dim3(256), 0, stream>>>(r1, l2W, l2B, batch, out);
}